// Round 7
// baseline (322.408 us; speedup 1.0000x reference)
//
#include <hip/hip_runtime.h>
#include <hip/hip_bf16.h>
#include <stdint.h>
#include <stddef.h>

#define B_  8192
#define T_  658
#define I_  7
#define TP  672     // T padded to multiple of 32 (GEMM1 K, A0 row stride)
#define D1_ 1024
#define D2_ 512
#define D3_ 128
#define NP4 768     // T padded to multiple of 128 (GEMM4 N)

// fused scan geometry
#define NB2 32      // batch rows per scan block
#define CT  32      // timesteps per chunk
#define NCH 21      // TP / CT
#define SCANBLKS 256            // B_ / NB2
#define SCTHR 320               // 1 consumer wave + 4 producer waves

#define CVTOT (D1_*TP + D2_*D1_ + D3_*D2_ + NP4*D3_)   // 1,376,256
#define CVBLKS 512              // grid-stride conversion blocks

typedef __bf16 bf16x8 __attribute__((ext_vector_type(8)));
typedef float  floatx4 __attribute__((ext_vector_type(4)));

__device__ __forceinline__ void gload_lds16(const void* g, void* l) {
    __builtin_amdgcn_global_load_lds(
        (const __attribute__((address_space(1))) void*)g,
        (__attribute__((address_space(3))) void*)l, 16, 0, 0);
}

__device__ __forceinline__ unsigned int pack_bf16x2(float a, float b) {
    unsigned int ua = __float_as_uint(a);
    unsigned int ub = __float_as_uint(b);
    ua += 0x7fffu + ((ua >> 16) & 1u);   // RNE to bf16 (finite inputs, |v|<=1)
    ub += 0x7fffu + ((ub >> 16) & 1u);
    return (ua >> 16) | (ub & 0xffff0000u);
}

// Stage chunk c for producer wave pw (rows 8pw..8pw+7) into lbuf (raw[c&1]).
// Per instruction: 8 lanes x 16B = 128B contiguous per row, 8 rows -> ~8 tx
// (vs ~56 with the per-thread unit loads of R4-R6). Global src rounded down
// to 16B (row bases are 8-mod-16 for odd rows); bounds proved in journal:
// S=8 chunks stay inside their row; S=4 last chunk ends exactly at buffer end.
template<int S>
__device__ __forceinline__ void stage_chunk(const float* __restrict__ x,
                                            float* lbuf, int b0, int pw, int l, int c) {
    const int srow = 8 * pw + (l >> 3);
    const float* sbase = x + (size_t)(b0 + srow) * (T_ * I_) - 2 * (srow & 1)
                         + (size_t)c * (CT * I_) + 4 * (l & 7);
    float* ldst = lbuf + pw * 2048;          // wave-uniform base (HW adds lane*16)
#pragma unroll
    for (int s = 0; s < S; ++s)
        gload_lds16(sbase + 32 * s, ldst + s * 256);
}

// ------- Kernel 1 (fused): producer/consumer scan + weight conversion -------
// blocks [0, SCANBLKS): own 32 batch rows, 320 threads.
//   Producer waves 1-4: stage raw x chunk it+1 to LDS via global_load_lds
//   (coalesced, direct-to-LDS), counted s_waitcnt vmcnt(8/4/0) (never drain),
//   then project chunk it (LDS raw -> 7-FMA dot -> lds_x). Each wave stages
//   and projects the SAME 8 rows -> own-wave vmcnt is the only sync needed.
//   Wave 0 lanes 0-31 run the tanh recurrence one chunk behind (r-form, 4-op
//   chain). Raw barrier (lgkmcnt(0)+s_barrier) keeps vmem in flight.
// blocks [SCANBLKS, +CVBLKS): grid-stride fp32->bf16 conversion of w1..w4.
__global__ __launch_bounds__(SCTHR) void scan_conv_kernel(
    const float* __restrict__ x, const float* __restrict__ h0,
    const float* __restrict__ Wih, const float* __restrict__ Whh,
    const float* __restrict__ bih, const float* __restrict__ bhh,
    __bf16* __restrict__ A0, float* __restrict__ hlast,
    const float* __restrict__ w1, const float* __restrict__ w2,
    const float* __restrict__ w3, const float* __restrict__ w4,
    __bf16* __restrict__ w1b, __bf16* __restrict__ w2b,
    __bf16* __restrict__ w3b, __bf16* __restrict__ w4b) {
    if (blockIdx.x >= SCANBLKS) {
        const int stride = CVBLKS * SCTHR;
        for (int i0 = (blockIdx.x - SCANBLKS) * SCTHR + threadIdx.x; i0 < CVTOT;
             i0 += stride) {
            int i = i0;
            if (i < D1_ * TP) {
                int r = i / TP, c = i - r * TP;
                w1b[i] = (__bf16)(c < T_ ? w1[r * T_ + c] : 0.0f);
                continue;
            }
            i -= D1_ * TP;
            if (i < D2_ * D1_) { w2b[i] = (__bf16)w2[i]; continue; }
            i -= D2_ * D1_;
            if (i < D3_ * D2_) { w3b[i] = (__bf16)w3[i]; continue; }
            i -= D3_ * D2_;
            {   // NP4*D3 elements
                int r = i / D3_, c = i - r * D3_;
                w4b[i] = (__bf16)(r < T_ ? w4[r * D3_ + c] : 0.0f);
            }
        }
        return;
    }

    __shared__ __align__(16) float lds_raw[2][8192];  // 64 KB raw x double-buffer
    __shared__ float        lds_x[2][CT][NB2 + 1];    // 8448 B, [buf][t][b]
    __shared__ unsigned int lds_o[2][NB2 * 17];        // 4352 B, packed results

    const int tid = threadIdx.x;
    const int b0 = blockIdx.x * NB2;

    const float whh = Whh[0], bh = bhh[0], bi = bih[0];
    float wih[I_];
#pragma unroll
    for (int j = 0; j < I_; ++j) wih[j] = Wih[j];

    const float C2L = 2.8853900817779268f;           // 2*log2(e)
    const float whhc = whh * C2L;
    const float m2w = -2.0f * whhc;

    float h = 0.0f, r = 0.0f;
    if (tid < NB2) {
        h = h0[b0 + tid];
        r = (1.0f - h) * 0.5f;                       // r-form of the state
    }
    unsigned int res[CT / 2];

    const int pw = (tid >> 6) - 1;                   // producer wave 0..3
    const int pl = tid & 63;

    // prologue: stage chunk 0 (latency paid once)
    if (tid >= 64) stage_chunk<8>(x, &lds_raw[0][0], b0, pw, pl, 0);

    for (int it = 0; it < NCH + 2; ++it) {
        // ---- producers: stage chunk it+1, counted wait, project chunk it ----
        if (tid >= 64 && it < NCH) {
            if (it + 1 <= NCH - 2) {
                stage_chunk<8>(x, &lds_raw[(it + 1) & 1][0], b0, pw, pl, it + 1);
                asm volatile("s_waitcnt vmcnt(8)" ::: "memory");
            } else if (it + 1 == NCH - 1) {
                stage_chunk<4>(x, &lds_raw[(it + 1) & 1][0], b0, pw, pl, it + 1);
                asm volatile("s_waitcnt vmcnt(4)" ::: "memory");
            } else {
                asm volatile("s_waitcnt vmcnt(0)" ::: "memory");
            }
            // project chunk it: row = (tid-64)>>3, unit u = (tid-64)&7 (4 t each)
            const int p = tid - 64;
            const int prow = p >> 3, pu = p & 7;
            const float* rbuf = &lds_raw[it & 1][(prow >> 3) * 2048 + (prow & 7) * 32];
            const int par2 = 2 * (prow & 1);         // 16B round-down compensation
            const int tmax = (it == NCH - 1) ? (T_ - it * CT) : CT;
#pragma unroll
            for (int n = 0; n < 4; ++n) {
                const int tt = pu * 4 + n;
                if (tt < tmax) {
                    const int F0 = tt * 7 + par2;
                    float s = bi;
#pragma unroll
                    for (int i = 0; i < I_; ++i) {
                        const int F = F0 + i;
                        s = fmaf(rbuf[(F >> 5) * 256 + (F & 31)], wih[i], s);
                    }
                    lds_x[it & 1][tt][prow] = s;
                }
            }
        }
        // ---- chain: wave 0 lanes 0-31 process chunk it-1 ----
        if (tid < NB2 && it >= 1 && it <= NCH) {
            const int ck = it - 1;
            const float* lx = &lds_x[ck & 1][0][tid];
            if (ck < NCH - 1) {
#pragma unroll
                for (int k = 0; k < CT; k += 2) {
                    float xv0 = lx[k * (NB2 + 1)];
                    float xv1 = lx[(k + 1) * (NB2 + 1)];
                    float c0 = fmaf(xv0 + bh, C2L, whhc);    // off-chain
                    float c1 = fmaf(xv1 + bh, C2L, whhc);    // off-chain
                    r = __builtin_amdgcn_rcpf(__builtin_amdgcn_exp2f(fmaf(m2w, r, c0)) + 1.0f);
                    float h0v = fmaf(-2.0f, r, 1.0f);        // off-chain
                    r = __builtin_amdgcn_rcpf(__builtin_amdgcn_exp2f(fmaf(m2w, r, c1)) + 1.0f);
                    h = fmaf(-2.0f, r, 1.0f);                // off-chain
                    res[k >> 1] = pack_bf16x2(h0v, h);
                }
            } else {
                const int nval = T_ - ck * CT;   // 18 on the last chunk
#pragma unroll
                for (int k = 0; k < CT; k += 2) {
                    float r0 = 0.0f, r1 = 0.0f;
                    if (k < nval) {
                        float xv0 = lx[k * (NB2 + 1)];
                        r = __builtin_amdgcn_rcpf(
                            __builtin_amdgcn_exp2f(fmaf(m2w, r, fmaf(xv0 + bh, C2L, whhc))) + 1.0f);
                        h = fmaf(-2.0f, r, 1.0f);
                        r0 = h;
                    }
                    if (k + 1 < nval) {
                        float xv1 = lx[(k + 1) * (NB2 + 1)];
                        r = __builtin_amdgcn_rcpf(
                            __builtin_amdgcn_exp2f(fmaf(m2w, r, fmaf(xv1 + bh, C2L, whhc))) + 1.0f);
                        h = fmaf(-2.0f, r, 1.0f);
                        r1 = h;
                    }
                    res[k >> 1] = pack_bf16x2(r0, r1);
                }
            }
#pragma unroll
            for (int j = 0; j < 16; ++j) lds_o[ck & 1][tid * 17 + j] = res[j];
        }
        // ---- store: chunk it-2 (written to lds_o[(it-2)&1] last iter) ----
        if (it >= 2 && tid < 128) {
            const int ck = it - 2;
            const int bl = tid >> 2, q = tid & 3;
            uint4 v;
            v.x = lds_o[ck & 1][bl * 17 + q * 4 + 0];
            v.y = lds_o[ck & 1][bl * 17 + q * 4 + 1];
            v.z = lds_o[ck & 1][bl * 17 + q * 4 + 2];
            v.w = lds_o[ck & 1][bl * 17 + q * 4 + 3];
            *(uint4*)(A0 + (size_t)(b0 + bl) * TP + ck * CT + q * 8) = v;
        }
        // ---- raw barrier: publish LDS (lgkm only), vmem stays in flight ----
        asm volatile("s_waitcnt lgkmcnt(0)" ::: "memory");
        __builtin_amdgcn_s_barrier();
        asm volatile("" ::: "memory");
    }
    if (tid < NB2) hlast[b0 + tid] = h;
}

// ---------------- Kernel 2: bf16 MFMA GEMM, C = relu(A @ W^T + bias) ---------
// BM x BN tile, BK=32, 256 threads = 4 waves in 2x2; wave tile (BM/2)x(BN/2).
// XCD-aware block decode: each XCD gets a contiguous m-range so its A panel
// is L2-resident. Requires gridDim.x % 8 == 0 for bijectivity (all satisfy).
template<int BM, int BN, int MINW>
__global__ __launch_bounds__(256, MINW) void gemm_bt(
    const __bf16* __restrict__ A, const __bf16* __restrict__ W,
    const float* __restrict__ bias, __bf16* __restrict__ outb,
    float* __restrict__ outf, int K, int Npad, int Nreal, int relu) {
    constexpr int MI = BM / 32;   // m fragments per wave
    constexpr int NJ = BN / 32;   // n fragments per wave
    constexpr int nA = BM / 64;   // 16B staging issues per thread, A tile
    constexpr int nB = BN / 64;   // 16B staging issues per thread, B tile
    __shared__ __align__(16) __bf16 As[BM * 32];
    __shared__ __align__(16) __bf16 Bs[BN * 32];

    const int tid = threadIdx.x;
    int mb, nb;
    {
        const int nbx = gridDim.x;
        const int bid = blockIdx.y * nbx + blockIdx.x;
        if ((nbx & 7) == 0) {
            const int mpx = nbx >> 3;          // m-blocks per XCD
            const int xcd = bid & 7, j = bid >> 3;
            mb = xcd * mpx + (j % mpx);
            nb = j / mpx;
        } else {
            mb = blockIdx.x; nb = blockIdx.y;
        }
    }
    const int m0 = mb * BM, n0 = nb * BN;
    const int lane = tid & 63, wave = tid >> 6;
    const int wm = (wave & 1) * (BM / 2), wn = (wave >> 1) * (BN / 2);
    const int quad = lane >> 4, l16 = lane & 15;

    const int eoff = tid * 8;
    const int rowS = eoff >> 5;            // 0..63
    const int colS = eoff & 31;
    const __bf16* gaa[nA];
    const __bf16* gbb[nB];
    __bf16* laa[nA];
    __bf16* lbb[nB];
#pragma unroll
    for (int c = 0; c < nA; ++c) {
        gaa[c] = A + (size_t)(m0 + rowS + c * 64) * K + colS;
        laa[c] = As + c * 2048 + (tid & 192) * 8;   // wave-uniform base
    }
#pragma unroll
    for (int c = 0; c < nB; ++c) {
        gbb[c] = W + (size_t)(n0 + rowS + c * 64) * K + colS;
        lbb[c] = Bs + c * 2048 + (tid & 192) * 8;
    }

    floatx4 acc[MI][NJ] = {};

    for (int k0 = 0; k0 < K; k0 += 32) {
#pragma unroll
        for (int c = 0; c < nA; ++c) gload_lds16(gaa[c] + k0, laa[c]);
#pragma unroll
        for (int c = 0; c < nB; ++c) gload_lds16(gbb[c] + k0, lbb[c]);
        __syncthreads();

        bf16x8 af[MI], bg[NJ];
#pragma unroll
        for (int i = 0; i < MI; ++i)
            af[i] = *(const bf16x8*)(As + (wm + i * 16 + l16) * 32 + quad * 8);
#pragma unroll
        for (int j = 0; j < NJ; ++j)
            bg[j] = *(const bf16x8*)(Bs + (wn + j * 16 + l16) * 32 + quad * 8);
#pragma unroll
        for (int i = 0; i < MI; ++i)
#pragma unroll
            for (int j = 0; j < NJ; ++j)
                acc[i][j] = __builtin_amdgcn_mfma_f32_16x16x32_bf16(af[i], bg[j], acc[i][j], 0, 0, 0);
        __syncthreads();
    }

    // Epilogue. C/D layout: col = lane&15, row = quad*4 + r (m89-verified)
#pragma unroll
    for (int j = 0; j < NJ; ++j) {
        const int n = n0 + wn + j * 16 + l16;
        const float bv = (n < Nreal) ? bias[n] : 0.0f;
#pragma unroll
        for (int i = 0; i < MI; ++i) {
#pragma unroll
            for (int r = 0; r < 4; ++r) {
                const int m = m0 + wm + i * 16 + quad * 4 + r;
                float v = acc[i][j][r] + bv;
                if (relu) v = fmaxf(v, 0.0f);
                if (outb) {
                    outb[(size_t)m * Npad + n] = (__bf16)v;
                } else if (n < Nreal) {
                    outf[(size_t)m * Nreal + n] = v;
                }
            }
        }
    }
}

extern "C" void kernel_launch(void* const* d_in, const int* in_sizes, int n_in,
                              void* d_out, int out_size, void* d_ws, size_t ws_size,
                              hipStream_t stream) {
    const float* x   = (const float*)d_in[0];
    const float* h0  = (const float*)d_in[1];
    const float* Wih = (const float*)d_in[2];
    const float* Whh = (const float*)d_in[3];
    const float* bih = (const float*)d_in[4];
    const float* bhh = (const float*)d_in[5];
    const float* w1  = (const float*)d_in[6];
    const float* b1  = (const float*)d_in[7];
    const float* w2  = (const float*)d_in[8];
    const float* b2  = (const float*)d_in[9];
    const float* w3  = (const float*)d_in[10];
    const float* b3  = (const float*)d_in[11];
    const float* w4  = (const float*)d_in[12];
    const float* b4  = (const float*)d_in[13];
    float* out = (float*)d_out;
    char* ws = (char*)d_ws;

    __bf16* w1b = (__bf16*)(ws + 0);          //  1,376,256
    __bf16* w2b = (__bf16*)(ws + 1376256);    //  1,048,576
    __bf16* w3b = (__bf16*)(ws + 2424832);    //    131,072
    __bf16* w4b = (__bf16*)(ws + 2555904);    //    196,608
    __bf16* A0  = (__bf16*)(ws + 2752512);    // 11,010,048  [B, TP]
    __bf16* A1  = (__bf16*)(ws + 13762560);   // 16,777,216  [B, D1]
    __bf16* A2  = (__bf16*)(ws + 30539776);   //  8,388,608  [B, D2]
    __bf16* A3  = (__bf16*)(ws + 38928384);   //  2,097,152  [B, D3]

    // Fused: scan (blocks 0..255, producer/consumer) + weight conversion
    scan_conv_kernel<<<SCANBLKS + CVBLKS, SCTHR, 0, stream>>>(
        x, h0, Wih, Whh, bih, bhh, A0, out + (size_t)B_ * T_,
        w1, w2, w3, w4, w1b, w2b, w3b, w4b);

    // GEMM1: 128x128 tile -> 512 blocks (2/CU), the 912 TF-class structure
    gemm_bt<128,128,2><<<dim3(64, 8), 256, 0, stream>>>(A0, w1b, b1, A1, nullptr, TP,  D1_, D1_, 1);
    // GEMM2: 128x64 tile -> 512 blocks; MINW=2 (MINW=4's 128-VGPR cap risks spill)
    gemm_bt<128,64,2> <<<dim3(64, 8), 256, 0, stream>>>(A1, w2b, b2, A2, nullptr, D1_, D2_, D2_, 1);
    gemm_bt<64,64,4>  <<<dim3(128, 2), 256, 0, stream>>>(A2, w3b, b3, A3, nullptr, D2_, D3_, D3_, 1);
    gemm_bt<64,128,4> <<<dim3(128, 6), 256, 0, stream>>>(A3, w4b, b4, nullptr, out, D3_, NP4, T_, 0);
}

// Round 8
// 315.544 us; speedup vs baseline: 1.0218x; 1.0218x over previous
//
#include <hip/hip_runtime.h>
#include <hip/hip_bf16.h>
#include <stdint.h>
#include <stddef.h>

#define B_  8192
#define T_  658
#define I_  7
#define TP  672     // T padded to multiple of 32 (GEMM1 K, A0 row stride)
#define D1_ 1024
#define D2_ 512
#define D3_ 128
#define NP4 768     // T padded to multiple of 128 (GEMM4 N)

// fused scan geometry
#define NB2 32      // batch rows per scan block
#define CT  32      // timesteps per chunk
#define NCH 21      // TP / CT
#define SCANBLKS 256            // B_ / NB2
#define SCTHR 320               // scan block threads: 1 consumer + 4 producer waves

#define CVTOT (D1_*TP + D2_*D1_ + D3_*D2_ + NP4*D3_)   // 1,376,256
#define CVBLKS ((CVTOT + SCTHR - 1) / SCTHR)            // 4301

typedef __bf16 bf16x8 __attribute__((ext_vector_type(8)));
typedef float  floatx4 __attribute__((ext_vector_type(4)));

__device__ __forceinline__ void gload_lds16(const void* g, void* l) {
    __builtin_amdgcn_global_load_lds(
        (const __attribute__((address_space(1))) void*)g,
        (__attribute__((address_space(3))) void*)l, 16, 0, 0);
}

template<int N> __device__ __forceinline__ void waitcnt_vm() {
    if constexpr (N == 0)      asm volatile("s_waitcnt vmcnt(0)" ::: "memory");
    else if constexpr (N == 2) asm volatile("s_waitcnt vmcnt(2)" ::: "memory");
    else if constexpr (N == 3) asm volatile("s_waitcnt vmcnt(3)" ::: "memory");
    else if constexpr (N == 4) asm volatile("s_waitcnt vmcnt(4)" ::: "memory");
    else                       asm volatile("s_waitcnt vmcnt(0)" ::: "memory");
}

__device__ __forceinline__ unsigned int pack_bf16x2(float a, float b) {
    unsigned int ua = __float_as_uint(a);
    unsigned int ub = __float_as_uint(b);
    ua += 0x7fffu + ((ua >> 16) & 1u);   // RNE to bf16 (finite inputs, |v|<=1)
    ub += 0x7fffu + ((ub >> 16) & 1u);
    return (ua >> 16) | (ub & 0xffff0000u);
}

// Load one unit (4 timesteps = 28 contiguous floats, 8B-aligned) of row data.
// tb = first timestep of the unit; guarded path only on the last chunk.
__device__ __forceinline__ void load_unit(const float* __restrict__ gp, int tb,
                                          float* __restrict__ xr) {
    if (tb <= T_ - 4) {
#pragma unroll
        for (int k = 0; k < 14; ++k) {       // 14 independent 8B loads
            const float2 f = *(const float2*)(gp + 2 * k);
            xr[2 * k]     = f.x;
            xr[2 * k + 1] = f.y;
        }
    } else {
        const int nfl = (T_ - tb) * I_;      // may be <= 0
#pragma unroll
        for (int k = 0; k < 28; ++k)
            xr[k] = (k < nfl) ? gp[k] : 0.0f;
    }
}

// ------- Kernel 1 (fused): producer/consumer scan + weight conversion -------
// R5 engine (best measured total): 320 threads; waves 1..4 = 256 producer
// threads, 1 unit each per chunk, register prefetch one chunk ahead; wave 0
// lanes 0-31 run the recurrence one chunk behind. Scan is at its BW floor
// (~25 us); frozen since R5.
__global__ __launch_bounds__(SCTHR) void scan_conv_kernel(
    const float* __restrict__ x, const float* __restrict__ h0,
    const float* __restrict__ Wih, const float* __restrict__ Whh,
    const float* __restrict__ bih, const float* __restrict__ bhh,
    __bf16* __restrict__ A0, float* __restrict__ hlast,
    const float* __restrict__ w1, const float* __restrict__ w2,
    const float* __restrict__ w3, const float* __restrict__ w4,
    __bf16* __restrict__ w1b, __bf16* __restrict__ w2b,
    __bf16* __restrict__ w3b, __bf16* __restrict__ w4b) {
    if (blockIdx.x >= SCANBLKS) {
        int i = (blockIdx.x - SCANBLKS) * SCTHR + threadIdx.x;
        if (i < D1_ * TP) {
            int r = i / TP, c = i - r * TP;
            w1b[i] = (__bf16)(c < T_ ? w1[r * T_ + c] : 0.0f);
            return;
        }
        i -= D1_ * TP;
        if (i < D2_ * D1_) { w2b[i] = (__bf16)w2[i]; return; }
        i -= D2_ * D1_;
        if (i < D3_ * D2_) { w3b[i] = (__bf16)w3[i]; return; }
        i -= D3_ * D2_;
        if (i < NP4 * D3_) {
            int r = i / D3_, c = i - r * D3_;
            w4b[i] = (__bf16)(r < T_ ? w4[r * D3_ + c] : 0.0f);
        }
        return;
    }

    __shared__ float        lds_x[2][CT][NB2 + 1];   // 8448 B, [buf][t][b]
    __shared__ unsigned int lds_o[2][NB2 * 17];       // 4352 B, packed results

    const int tid = threadIdx.x;
    const int b0 = blockIdx.x * NB2;

    const float whh = Whh[0], bh = bhh[0], bi = bih[0];
    float wih[I_];
#pragma unroll
    for (int j = 0; j < I_; ++j) wih[j] = Wih[j];

    const float C2L = 2.8853900817779268f;           // 2*log2(e)
    const float whhc = whh * C2L;
    const float m2w = -2.0f * whhc;

    float h = 0.0f, r = 0.0f;
    if (tid < NB2) {
        h = h0[b0 + tid];
        r = (1.0f - h) * 0.5f;                       // r-form of the state
    }
    unsigned int res[CT / 2];

    // producer geometry: unit = tid-64 in [0,256); row = unit>>3, u = unit&7
    const int unit = tid - 64;
    const int prow = unit >> 3, pu = unit & 7;
    const float* gpu = x + (size_t)(b0 + prow) * (T_ * I_) + (size_t)(pu * 4) * I_;
    float xr[28];
    if (tid >= 64) load_unit(gpu, pu * 4, xr);       // prologue: chunk 0

    for (int it = 0; it < NCH + 2; ++it) {
        // ---- producers: write chunk `it` (in regs) to lds_x[it&1], then
        //      issue chunk it+1's loads ----
        if (tid >= 64 && it < NCH) {
#pragma unroll
            for (int n = 0; n < 4; ++n) {
                float s = bi;
#pragma unroll
                for (int i = 0; i < I_; ++i)
                    s = fmaf(xr[n * 7 + i], wih[i], s);
                lds_x[it & 1][pu * 4 + n][prow] = s;
            }
            if (it + 1 < NCH)
                load_unit(gpu + (size_t)(it + 1) * (CT * I_),
                          (it + 1) * CT + pu * 4, xr);
        }
        // ---- chain: wave 0 lanes 0-31 process chunk it-1 ----
        if (tid < NB2 && it >= 1 && it <= NCH) {
            const int ck = it - 1;
            const float* lx = &lds_x[ck & 1][0][tid];
            if (ck < NCH - 1) {
#pragma unroll
                for (int k = 0; k < CT; k += 2) {
                    float xv0 = lx[k * (NB2 + 1)];
                    float xv1 = lx[(k + 1) * (NB2 + 1)];
                    float c0 = fmaf(xv0 + bh, C2L, whhc);    // off-chain
                    float c1 = fmaf(xv1 + bh, C2L, whhc);    // off-chain
                    r = __builtin_amdgcn_rcpf(__builtin_amdgcn_exp2f(fmaf(m2w, r, c0)) + 1.0f);
                    float h0v = fmaf(-2.0f, r, 1.0f);        // off-chain
                    r = __builtin_amdgcn_rcpf(__builtin_amdgcn_exp2f(fmaf(m2w, r, c1)) + 1.0f);
                    h = fmaf(-2.0f, r, 1.0f);                // off-chain
                    res[k >> 1] = pack_bf16x2(h0v, h);
                }
            } else {
                const int nval = T_ - ck * CT;   // 18 on the last chunk
#pragma unroll
                for (int k = 0; k < CT; k += 2) {
                    float r0 = 0.0f, r1 = 0.0f;
                    if (k < nval) {
                        float xv0 = lx[k * (NB2 + 1)];
                        r = __builtin_amdgcn_rcpf(
                            __builtin_amdgcn_exp2f(fmaf(m2w, r, fmaf(xv0 + bh, C2L, whhc))) + 1.0f);
                        h = fmaf(-2.0f, r, 1.0f);
                        r0 = h;
                    }
                    if (k + 1 < nval) {
                        float xv1 = lx[(k + 1) * (NB2 + 1)];
                        r = __builtin_amdgcn_rcpf(
                            __builtin_amdgcn_exp2f(fmaf(m2w, r, fmaf(xv1 + bh, C2L, whhc))) + 1.0f);
                        h = fmaf(-2.0f, r, 1.0f);
                        r1 = h;
                    }
                    res[k >> 1] = pack_bf16x2(r0, r1);
                }
            }
#pragma unroll
            for (int j = 0; j < 16; ++j) lds_o[ck & 1][tid * 17 + j] = res[j];
        }
        // ---- store: chunk it-2 (written to lds_o[(it-2)&1] last iter) ----
        if (it >= 2 && tid < 128) {
            const int ck = it - 2;
            const int bl = tid >> 2, q = tid & 3;
            uint4 v;
            v.x = lds_o[ck & 1][bl * 17 + q * 4 + 0];
            v.y = lds_o[ck & 1][bl * 17 + q * 4 + 1];
            v.z = lds_o[ck & 1][bl * 17 + q * 4 + 2];
            v.w = lds_o[ck & 1][bl * 17 + q * 4 + 3];
            *(uint4*)(A0 + (size_t)(b0 + bl) * TP + ck * CT + q * 8) = v;
        }
        __syncthreads();
    }
    if (tid < NB2) hlast[b0 + tid] = h;
}

// ---------------- Kernel 2: bf16 MFMA GEMM, C = relu(A @ W^T + bias) ---------
// R8: 2-phase stage-ahead pipeline (T3 minimum recipe). Per k-iter:
//   stage(t+1 -> buf^1)  [gload_lds, issued FIRST]
//   s_waitcnt vmcnt(LPT) [counted: waits tile t's loads, t+1's stay in flight]
//   s_barrier            [publish buf[cur] to all waves]
//   ds_read + MFMA on buf[cur]
//   s_waitcnt lgkmcnt(0) + sched_barrier(0)  [reads retired before...]
//   s_barrier            [...any wave re-stages this buffer next iter]
// Load latency+service overlaps the previous iteration's ds_read+MFMA —
// removes the serial stage->drain->compute cadence (__syncthreads lowered
// vmcnt(0) every iter) that capped all tilings at ~320-450 TF.
template<int BM, int BN, int MINW>
__global__ __launch_bounds__(256, MINW) void gemm_bt(
    const __bf16* __restrict__ A, const __bf16* __restrict__ W,
    const float* __restrict__ bias, __bf16* __restrict__ outb,
    float* __restrict__ outf, int K, int Npad, int Nreal, int relu) {
    constexpr int MI = BM / 32;   // m fragments per wave
    constexpr int NJ = BN / 32;   // n fragments per wave
    constexpr int nA = BM / 64;   // 16B staging issues per thread, A tile
    constexpr int nB = BN / 64;   // 16B staging issues per thread, B tile
    constexpr int LPT = nA + nB;  // issues in flight for one staged tile
    __shared__ __align__(16) __bf16 As[2 * BM * 32];
    __shared__ __align__(16) __bf16 Bs[2 * BN * 32];

    const int tid = threadIdx.x;
    int mb, nb;
    {
        const int nbx = gridDim.x;
        const int bid = blockIdx.y * nbx + blockIdx.x;
        if ((nbx & 7) == 0) {
            const int mpx = nbx >> 3;          // m-blocks per XCD
            const int xcd = bid & 7, j = bid >> 3;
            mb = xcd * mpx + (j % mpx);
            nb = j / mpx;
        } else {
            mb = blockIdx.x; nb = blockIdx.y;
        }
    }
    const int m0 = mb * BM, n0 = nb * BN;
    const int lane = tid & 63, wave = tid >> 6;
    const int wm = (wave & 1) * (BM / 2), wn = (wave >> 1) * (BN / 2);
    const int quad = lane >> 4, l16 = lane & 15;

    const int eoff = tid * 8;
    const int rowS = eoff >> 5;            // 0..63
    const int colS = eoff & 31;
    const __bf16* gaa[nA];
    const __bf16* gbb[nB];
#pragma unroll
    for (int c = 0; c < nA; ++c)
        gaa[c] = A + (size_t)(m0 + rowS + c * 64) * K + colS;
#pragma unroll
    for (int c = 0; c < nB; ++c)
        gbb[c] = W + (size_t)(n0 + rowS + c * 64) * K + colS;
    __bf16* laaB = As + (tid & 192) * 8;   // wave-uniform base (+ cur*BM*32 + c*2048)
    __bf16* lbbB = Bs + (tid & 192) * 8;

    auto stage = [&](int t, int cu) {
        const int k0 = t * 32;
#pragma unroll
        for (int c = 0; c < nA; ++c)
            gload_lds16(gaa[c] + k0, laaB + cu * (BM * 32) + c * 2048);
#pragma unroll
        for (int c = 0; c < nB; ++c)
            gload_lds16(gbb[c] + k0, lbbB + cu * (BN * 32) + c * 2048);
    };

    floatx4 acc[MI][NJ] = {};

    stage(0, 0);
    int cur = 0;
    const int NT = K / 32;
    for (int t = 0; t < NT; ++t) {
        if (t + 1 < NT) {
            stage(t + 1, cur ^ 1);
            waitcnt_vm<LPT>();             // tile t's loads done; t+1's in flight
        } else {
            waitcnt_vm<0>();
        }
        __builtin_amdgcn_s_barrier();      // buf[cur] visible to all waves
        asm volatile("" ::: "memory");

        bf16x8 af[MI], bg[NJ];
#pragma unroll
        for (int i = 0; i < MI; ++i)
            af[i] = *(const bf16x8*)(As + cur * (BM * 32) + (wm + i * 16 + l16) * 32 + quad * 8);
#pragma unroll
        for (int j = 0; j < NJ; ++j)
            bg[j] = *(const bf16x8*)(Bs + cur * (BN * 32) + (wn + j * 16 + l16) * 32 + quad * 8);
#pragma unroll
        for (int i = 0; i < MI; ++i)
#pragma unroll
            for (int j = 0; j < NJ; ++j)
                acc[i][j] = __builtin_amdgcn_mfma_f32_16x16x32_bf16(af[i], bg[j], acc[i][j], 0, 0, 0);

        asm volatile("s_waitcnt lgkmcnt(0)" ::: "memory");
        __builtin_amdgcn_sched_barrier(0); // rule #18: pin reads retired here
        __builtin_amdgcn_s_barrier();      // now buf[cur] may be re-staged
        cur ^= 1;
    }

    // Epilogue. C/D layout: col = lane&15, row = quad*4 + r (m89-verified)
#pragma unroll
    for (int j = 0; j < NJ; ++j) {
        const int n = n0 + wn + j * 16 + l16;
        const float bv = (n < Nreal) ? bias[n] : 0.0f;
#pragma unroll
        for (int i = 0; i < MI; ++i) {
#pragma unroll
            for (int r = 0; r < 4; ++r) {
                const int m = m0 + wm + i * 16 + quad * 4 + r;
                float v = acc[i][j][r] + bv;
                if (relu) v = fmaxf(v, 0.0f);
                if (outb) {
                    outb[(size_t)m * Npad + n] = (__bf16)v;
                } else if (n < Nreal) {
                    outf[(size_t)m * Nreal + n] = v;
                }
            }
        }
    }
}

extern "C" void kernel_launch(void* const* d_in, const int* in_sizes, int n_in,
                              void* d_out, int out_size, void* d_ws, size_t ws_size,
                              hipStream_t stream) {
    const float* x   = (const float*)d_in[0];
    const float* h0  = (const float*)d_in[1];
    const float* Wih = (const float*)d_in[2];
    const float* Whh = (const float*)d_in[3];
    const float* bih = (const float*)d_in[4];
    const float* bhh = (const float*)d_in[5];
    const float* w1  = (const float*)d_in[6];
    const float* b1  = (const float*)d_in[7];
    const float* w2  = (const float*)d_in[8];
    const float* b2  = (const float*)d_in[9];
    const float* w3  = (const float*)d_in[10];
    const float* b3  = (const float*)d_in[11];
    const float* w4  = (const float*)d_in[12];
    const float* b4  = (const float*)d_in[13];
    float* out = (float*)d_out;
    char* ws = (char*)d_ws;

    __bf16* w1b = (__bf16*)(ws + 0);          //  1,376,256
    __bf16* w2b = (__bf16*)(ws + 1376256);    //  1,048,576
    __bf16* w3b = (__bf16*)(ws + 2424832);    //    131,072
    __bf16* w4b = (__bf16*)(ws + 2555904);    //    196,608
    __bf16* A0  = (__bf16*)(ws + 2752512);    // 11,010,048  [B, TP]
    __bf16* A1  = (__bf16*)(ws + 13762560);   // 16,777,216  [B, D1]
    __bf16* A2  = (__bf16*)(ws + 30539776);   //  8,388,608  [B, D2]
    __bf16* A3  = (__bf16*)(ws + 38928384);   //  2,097,152  [B, D3]

    // Fused: scan (blocks 0..255, producer/consumer) + weight conversion
    scan_conv_kernel<<<SCANBLKS + CVBLKS, SCTHR, 0, stream>>>(
        x, h0, Wih, Whh, bih, bhh, A0, out + (size_t)B_ * T_,
        w1, w2, w3, w4, w1b, w2b, w3b, w4b);

    // 2-phase pipelined GEMMs
    gemm_bt<128,128,2><<<dim3(64, 8), 256, 0, stream>>>(A0, w1b, b1, A1, nullptr, TP,  D1_, D1_, 1);
    gemm_bt<128,64,2> <<<dim3(64, 8), 256, 0, stream>>>(A1, w2b, b2, A2, nullptr, D1_, D2_, D2_, 1);
    gemm_bt<64,64,2>  <<<dim3(128, 2), 256, 0, stream>>>(A2, w3b, b3, A3, nullptr, D2_, D3_, D3_, 1);
    gemm_bt<64,128,2> <<<dim3(128, 6), 256, 0, stream>>>(A3, w4b, b4, nullptr, out, D3_, NP4, T_, 0);
}